// Round 4
// baseline (10868.802 us; speedup 1.0000x reference)
//
#include <hip/hip_runtime.h>
#include <math.h>

#define Bn   128
#define Sn   336
#define INd  64
#define Hn   1024
#define Tn   96
#define G4   4096
#define KCE  34     // enc k-chunks: [x(64) | h(1024)]
#define KCD  65     // dec k-chunks: [ctx(1024) | h(1024) | prev_y | pad]
#define KCQ  32     // attn query k-chunks
#define NBLK 256
#define SHALF 168   // S split per attention partial block

typedef __attribute__((ext_vector_type(8))) short short8;
typedef __attribute__((ext_vector_type(4))) float floatx4;
typedef __attribute__((ext_vector_type(4))) unsigned int uintx4;
typedef unsigned long long u64t;

__device__ __forceinline__ float sigmoidf_(float x){ return 1.0f/(1.0f+expf(-x)); }

__device__ __forceinline__ unsigned short f2bf(float f){
    union { float f; unsigned u; } v; v.f = f;
    unsigned r = v.u + 0x7fffu + ((v.u >> 16) & 1u);
    return (unsigned short)(r >> 16);
}
__device__ __forceinline__ float bflo(unsigned u){ union{unsigned u; float f;} v; v.u = u << 16;        return v.f; }
__device__ __forceinline__ float bfhi(unsigned u){ union{unsigned u; float f;} v; v.u = u & 0xffff0000u; return v.f; }
__device__ __forceinline__ void unpack8v(uintx4 v, float* f){
    f[0]=bflo(v.x); f[1]=bfhi(v.x); f[2]=bflo(v.y); f[3]=bfhi(v.y);
    f[4]=bflo(v.z); f[5]=bfhi(v.z); f[6]=bflo(v.w); f[7]=bfhi(v.w);
}

// ---- LLC-coherent (agent-scope, L2-bypassing) access helpers -------------
union Frag16 { u64t q[2]; short8 s8; uintx4 u4; };
union F2 { u64t q; float f[2]; };

__device__ __forceinline__ short8 ld_cg_s8(const unsigned short* p){
    Frag16 r;
    r.q[0] = __hip_atomic_load((const u64t*)p,     __ATOMIC_RELAXED, __HIP_MEMORY_SCOPE_AGENT);
    r.q[1] = __hip_atomic_load((const u64t*)p + 1, __ATOMIC_RELAXED, __HIP_MEMORY_SCOPE_AGENT);
    return r.s8;
}
__device__ __forceinline__ uintx4 ld_cg_u4(const unsigned short* p){
    Frag16 r;
    r.q[0] = __hip_atomic_load((const u64t*)p,     __ATOMIC_RELAXED, __HIP_MEMORY_SCOPE_AGENT);
    r.q[1] = __hip_atomic_load((const u64t*)p + 1, __ATOMIC_RELAXED, __HIP_MEMORY_SCOPE_AGENT);
    return r.u4;
}
__device__ __forceinline__ void st_cg16(unsigned short* p, unsigned short v){
    asm volatile("global_store_short %0, %1, off sc0 sc1" :: "v"(p), "v"((unsigned)v) : "memory");
}
__device__ __forceinline__ void st_cg32(unsigned short* p, unsigned v){
    asm volatile("global_store_dword %0, %1, off sc0 sc1" :: "v"(p), "v"(v) : "memory");
}
__device__ __forceinline__ void st_cg64(float* p, float a, float b){
    F2 v; v.f[0] = a; v.f[1] = b;
    __hip_atomic_store((u64t*)p, v.q, __ATOMIC_RELAXED, __HIP_MEMORY_SCOPE_AGENT);
}
__device__ __forceinline__ F2 ld_cg64(const float* p){
    F2 v; v.q = __hip_atomic_load((const u64t*)p, __ATOMIC_RELAXED, __HIP_MEMORY_SCOPE_AGENT);
    return v;
}

// Broadcast barrier: zero atomic fan-in. Every block STOREs its step to its
// own cacheline (parallel, no LLC RMW serialization). Block 0's wave 0 sweeps
// all 256 slots (4 agent loads/lane) and publishes a release word that all
// other blocks poll. Chain ~2 LLC round trips. Monotonic counters, no reset.
// Layout (u32): arrive[b] = b*32 (128B apart), release = 8192.
__device__ __forceinline__ void gbar3(unsigned* bb, unsigned step){
    asm volatile("s_waitcnt vmcnt(0)" ::: "memory");
    __syncthreads();
    if (threadIdx.x == 0)
        __hip_atomic_store(bb + blockIdx.x*32, step, __ATOMIC_RELAXED, __HIP_MEMORY_SCOPE_AGENT);
    if (blockIdx.x == 0){
        if (threadIdx.x < 64){
            const int l = threadIdx.x;
            for (;;){
                unsigned a0 = __hip_atomic_load(bb + (l      )*32, __ATOMIC_RELAXED, __HIP_MEMORY_SCOPE_AGENT);
                unsigned a1 = __hip_atomic_load(bb + (l +  64)*32, __ATOMIC_RELAXED, __HIP_MEMORY_SCOPE_AGENT);
                unsigned a2 = __hip_atomic_load(bb + (l + 128)*32, __ATOMIC_RELAXED, __HIP_MEMORY_SCOPE_AGENT);
                unsigned a3 = __hip_atomic_load(bb + (l + 192)*32, __ATOMIC_RELAXED, __HIP_MEMORY_SCOPE_AGENT);
                int ok = (a0 >= step) && (a1 >= step) && (a2 >= step) && (a3 >= step);
                if (__all(ok)) break;
                __builtin_amdgcn_s_sleep(1);
            }
            if (l == 0)
                __hip_atomic_store(bb + 8192, step, __ATOMIC_RELAXED, __HIP_MEMORY_SCOPE_AGENT);
        }
    } else {
        if (threadIdx.x == 0){
            while (__hip_atomic_load(bb + 8192, __ATOMIC_RELAXED, __HIP_MEMORY_SCOPE_AGENT) < step)
                __builtin_amdgcn_s_sleep(1);
        }
    }
    __syncthreads();
}

// ===================== fragment-order packing ==============================
__global__ void pack_encf(const float* __restrict__ Wih, const float* __restrict__ Whh,
                          const float* __restrict__ bih, const float* __restrict__ bhh,
                          unsigned short* __restrict__ Wp, float* __restrict__ bc){
    long n = (long)256*KCE*512;
    for (long idx = (long)blockIdx.x*256 + threadIdx.x; idx < n; idx += (long)gridDim.x*256){
        int j = (int)(idx & 7), l = (int)((idx >> 3) & 63);
        int kc = (int)((idx >> 9) % KCE);
        int s  = (int)(idx / (KCE*512));
        int c = l & 15, kg = l >> 4;
        int k = kc*32 + kg*8 + j;
        int gate = s & 3, unit = (s >> 2)*16 + c;
        int orig = gate*Hn + unit;
        float v = (k < INd) ? Wih[orig*INd + k] : Whh[(size_t)orig*Hn + (k - INd)];
        Wp[idx] = f2bf(v);
    }
    int tid = blockIdx.x*256 + threadIdx.x;
    if (tid < G4){
        int g = (tid >> 4) & 3, u = (tid >> 6)*16 + (tid & 15);
        int orig = g*Hn + u;
        bc[tid] = bih[orig] + bhh[orig];
    }
}

__global__ void pack_decf(const float* __restrict__ Wih, const float* __restrict__ Whh,
                          const float* __restrict__ bih, const float* __restrict__ bhh,
                          unsigned short* __restrict__ Wp, float* __restrict__ bc){
    long n = (long)256*KCD*512;
    for (long idx = (long)blockIdx.x*256 + threadIdx.x; idx < n; idx += (long)gridDim.x*256){
        int j = (int)(idx & 7), l = (int)((idx >> 3) & 63);
        int kc = (int)((idx >> 9) % KCD);
        int s  = (int)(idx / (KCD*512));
        int c = l & 15, kg = l >> 4;
        int k = kc*32 + kg*8 + j;
        int gate = s & 3, unit = (s >> 2)*16 + c;
        int orig = gate*Hn + unit;
        float v;
        if (k < Hn)          v = Wih[(size_t)orig*(Hn+1) + 1 + k];     // ctx
        else if (k < 2*Hn)   v = Whh[(size_t)orig*Hn + (k - Hn)];      // h
        else if (k == 2*Hn)  v = Wih[(size_t)orig*(Hn+1)];             // prev_y
        else                 v = 0.0f;                                  // pad
        Wp[idx] = f2bf(v);
    }
    int tid = blockIdx.x*256 + threadIdx.x;
    if (tid < G4){
        int g = (tid >> 4) & 3, u = (tid >> 6)*16 + (tid & 15);
        int orig = g*Hn + u;
        bc[tid] = bih[orig] + bhh[orig];
    }
}

__global__ void pack_attnf(const float* __restrict__ w, unsigned short* __restrict__ Wp){
    int n = 64*KCQ*512;
    for (int idx = blockIdx.x*256 + threadIdx.x; idx < n; idx += gridDim.x*256){
        int j = idx & 7, l = (idx >> 3) & 63;
        int kc = (idx >> 9) & 31;
        int s  = idx >> 14;
        int nn = s*16 + (l & 15);
        int k = kc*32 + (l >> 4)*8 + j;
        Wp[idx] = f2bf(w[(size_t)nn*Hn + k]);
    }
}

// src A-fragments: [t][rg(8)][kc(2)][lane][8]; row b = rg*16 + (l&15)
__global__ void conv_srcf(const float* __restrict__ s, unsigned short* __restrict__ d){
    int n = Sn*8*2*512;
    for (int idx = blockIdx.x*256 + threadIdx.x; idx < n; idx += gridDim.x*256){
        int j = idx & 7, l = (idx >> 3) & 63;
        int kc = (idx >> 9) & 1, rg = (idx >> 10) & 7, t = idx >> 13;
        int b = rg*16 + (l & 15);
        int k = kc*32 + (l >> 4)*8 + j;
        d[idx] = f2bf(s[((size_t)b*Sn + t)*INd + k]);
    }
}

__global__ void init_ws(unsigned short* __restrict__ hf0, float* __restrict__ cbuf,
                        unsigned short* __restrict__ A0, unsigned short* __restrict__ A1,
                        unsigned* __restrict__ bars, unsigned* __restrict__ pcnt){
    int t0 = blockIdx.x*256 + threadIdx.x;
    for (int i = t0; i < 8*KCD*512; i += gridDim.x*256){
        A0[i] = 0; A1[i] = 0;
        if (i < 8*32*512) hf0[i] = 0;
        if (i < Bn*Hn) cbuf[i] = 0.0f;
        if (i < 32768) bars[i] = 0;
        if (i < 4096)  pcnt[i] = 0;
    }
}

// XCD-aware swizzle: blocks on XCD k own y in [k*8, k*8+8) -> per-XCD weight
// slice (enc ~1.1MB, dec ~2.1MB) stays L2-resident across all steps.
__device__ __forceinline__ void swz(int b, int& x, int& y){
    int xcd = b & 7, li = b >> 3;
    y = xcd*8 + (li & 7);
    x = li >> 3;
}

// fc dot: pred[b] = h[b,:] . fcW  (lane0 of the wave holds the result)
__device__ __forceinline__ float fcdot(const unsigned short* __restrict__ hplain,
                                       const float* __restrict__ fcW, int b, int l){
    const unsigned short* hp = hplain + (size_t)b*Hn + l*16;
    uintx4 h0 = ld_cg_u4(hp), h1 = ld_cg_u4(hp + 8);
    float hf[16]; unpack8v(h0, hf); unpack8v(h1, hf + 8);
    float p = 0.0f;
    #pragma unroll
    for (int i = 0; i < 16; i++) p = fmaf(hf[i], fcW[l*16 + i], p);
    #pragma unroll
    for (int off = 32; off; off >>= 1) p += __shfl_down(p, off);
    return p;
}

// ===================== persistent encoder: 336 steps, 1 barrier each =======
__global__ __launch_bounds__(256, 1)
void enc_loop(const unsigned short* __restrict__ srcfrag,  // [336][8][2][512]
              const unsigned short* __restrict__ Wf,       // [256][KCE][512]
              const float* __restrict__ bc, float* __restrict__ cbuf,
              unsigned short* __restrict__ hf0,            // [8][32][512]
              unsigned short* __restrict__ hf1,
              unsigned short* __restrict__ enco,
              unsigned short* __restrict__ adec0,          // [8][KCD][512]
              unsigned* __restrict__ bar)
{
    __shared__ float red[2][16][65];
    const int tid = threadIdx.x, l = tid & 63, w = tid >> 6;
    const int rgw = w & 1, kh = w >> 1;
    int x, y; swz(blockIdx.x, x, y);
    const int rg = x*2 + rgw;
    const int m0 = rg*16;
    const unsigned short* Bf = Wf + (size_t)(4*y)*KCE*512 + l*8;

    const int col = l & 15, q = l >> 4;
    const int u = y*16 + col;
    const float bi  = bc[y*64 + col];
    const float bf_ = bc[y*64 + 16 + col];
    const float bg  = bc[y*64 + 32 + col];
    const float bo  = bc[y*64 + 48 + col];
    const int lsh = ((u >> 3) & 3) * 16;

    unsigned bstep = 0;
    for (int t = 0; t < Sn; t++){
        const unsigned short* hin = (t & 1) ? hf1 : hf0;
        unsigned short* hout      = (t & 1) ? hf0 : hf1;
        const unsigned short* Ah = hin + (size_t)rg*32*512 + l*8;
        floatx4 acc0={0,0,0,0}, acc1={0,0,0,0}, acc2={0,0,0,0}, acc3={0,0,0,0};

        if (kh == 0){
            // prefetch all LLC h-fragments off the MFMA critical path
            short8 ah[15];
            #pragma unroll
            for (int hc = 0; hc < 15; hc++) ah[hc] = ld_cg_s8(Ah + hc*512);
            const unsigned short* Ax = srcfrag + ((size_t)t*8 + rg)*2*512 + l*8;
            #pragma unroll
            for (int kc = 0; kc < 2; kc++){
                short8 a  = *(const short8*)(Ax + kc*512);
                short8 b0 = *(const short8*)(Bf + (0*KCE + kc)*512);
                short8 b1 = *(const short8*)(Bf + (1*KCE + kc)*512);
                short8 b2 = *(const short8*)(Bf + (2*KCE + kc)*512);
                short8 b3 = *(const short8*)(Bf + (3*KCE + kc)*512);
                acc0 = __builtin_amdgcn_mfma_f32_16x16x32_bf16(a, b0, acc0, 0, 0, 0);
                acc1 = __builtin_amdgcn_mfma_f32_16x16x32_bf16(a, b1, acc1, 0, 0, 0);
                acc2 = __builtin_amdgcn_mfma_f32_16x16x32_bf16(a, b2, acc2, 0, 0, 0);
                acc3 = __builtin_amdgcn_mfma_f32_16x16x32_bf16(a, b3, acc3, 0, 0, 0);
            }
            #pragma unroll
            for (int hc = 0; hc < 15; hc++){
                short8 b0 = *(const short8*)(Bf + (0*KCE + hc + 2)*512);
                short8 b1 = *(const short8*)(Bf + (1*KCE + hc + 2)*512);
                short8 b2 = *(const short8*)(Bf + (2*KCE + hc + 2)*512);
                short8 b3 = *(const short8*)(Bf + (3*KCE + hc + 2)*512);
                acc0 = __builtin_amdgcn_mfma_f32_16x16x32_bf16(ah[hc], b0, acc0, 0, 0, 0);
                acc1 = __builtin_amdgcn_mfma_f32_16x16x32_bf16(ah[hc], b1, acc1, 0, 0, 0);
                acc2 = __builtin_amdgcn_mfma_f32_16x16x32_bf16(ah[hc], b2, acc2, 0, 0, 0);
                acc3 = __builtin_amdgcn_mfma_f32_16x16x32_bf16(ah[hc], b3, acc3, 0, 0, 0);
            }
        } else {
            short8 ah[17];
            #pragma unroll
            for (int i = 0; i < 17; i++) ah[i] = ld_cg_s8(Ah + (15 + i)*512);
            #pragma unroll
            for (int i = 0; i < 17; i++){
                short8 b0 = *(const short8*)(Bf + (0*KCE + i + 17)*512);
                short8 b1 = *(const short8*)(Bf + (1*KCE + i + 17)*512);
                short8 b2 = *(const short8*)(Bf + (2*KCE + i + 17)*512);
                short8 b3 = *(const short8*)(Bf + (3*KCE + i + 17)*512);
                acc0 = __builtin_amdgcn_mfma_f32_16x16x32_bf16(ah[i], b0, acc0, 0, 0, 0);
                acc1 = __builtin_amdgcn_mfma_f32_16x16x32_bf16(ah[i], b1, acc1, 0, 0, 0);
                acc2 = __builtin_amdgcn_mfma_f32_16x16x32_bf16(ah[i], b2, acc2, 0, 0, 0);
                acc3 = __builtin_amdgcn_mfma_f32_16x16x32_bf16(ah[i], b3, acc3, 0, 0, 0);
            }
            #pragma unroll
            for (int r = 0; r < 4; r++){
                red[rgw][ 0 + r][l] = acc0[r];
                red[rgw][ 4 + r][l] = acc1[r];
                red[rgw][ 8 + r][l] = acc2[r];
                red[rgw][12 + r][l] = acc3[r];
            }
        }
        __syncthreads();
        if (kh == 0){
            #pragma unroll
            for (int r = 0; r < 4; r++){
                acc0[r] += red[rgw][ 0 + r][l];
                acc1[r] += red[rgw][ 4 + r][l];
                acc2[r] += red[rgw][ 8 + r][l];
                acc3[r] += red[rgw][12 + r][l];
            }
            #pragma unroll
            for (int r = 0; r < 4; r++){
                const int m = m0 + q*4 + r;
                float gi = acc0[r] + bi;
                float gf = acc1[r] + bf_;
                float gg = acc2[r] + bg;
                float go = acc3[r] + bo;
                float co = cbuf[(size_t)m*Hn + u];
                float cn = sigmoidf_(gf)*co + sigmoidf_(gi)*tanhf(gg);
                float hv = sigmoidf_(go)*tanhf(cn);
                cbuf[(size_t)m*Hn + u] = cn;
                unsigned short hb = f2bf(hv);
                const int lanep = (q*4 + r) + lsh;
                st_cg16(hout + (((size_t)rg*32 + (u >> 5))*64 + lanep)*8 + (u & 7), hb);
                enco[((size_t)m*Sn + t)*Hn + u] = hb;   // cached; flushed at kernel end
                if (t == Sn-1) adec0[(((size_t)rg*KCD + 32 + (u >> 5))*64 + lanep)*8 + (u & 7)] = hb;
            }
        }
        bstep++; gbar3(bar, bstep);
    }
}

// ---- phase-B pipeline macros: 4-deep static prefetch ----------------------
#define BLOAD(P, I) { const size_t s_ = (size_t)(sb + 8*(I)); \
    buf_a##P = ebase[s_*128]; buf_b##P = ebase[s_*128 + 1]; }
#define BPROC(P) { \
    float ev[16]; unpack8v(buf_a##P, ev); unpack8v(buf_b##P, ev + 8); \
    float pt = 0.0f; \
    _Pragma("unroll") for (int i_ = 0; i_ < 16; i_++) pt = fmaf(qv[i_], ev[i_], pt); \
    _Pragma("unroll") for (int o_ = 32; o_; o_ >>= 1) pt += __shfl_down(pt, o_); \
    float e_ = __shfl(pt, 0); \
    float mn_ = fmaxf(mx, e_); \
    float corr_ = expf(mx - mn_); \
    float p_ = expf(e_ - mn_); \
    lsum = lsum*corr_ + p_; \
    if (corr_ != 1.0f){ _Pragma("unroll") for (int i_ = 0; i_ < 16; i_++) cacc[i_] *= corr_; } \
    _Pragma("unroll") for (int i_ = 0; i_ < 16; i_++) cacc[i_] = fmaf(p_, ev[i_], cacc[i_]); \
    mx = mn_; }

// ===================== persistent decoder: 96 steps, 3 barriers each =======
// 256 blocks x 512 thr (8 waves: rgw=w&1, ks=w>>1).
// Phase A: dec-GEMM h-part + attnq split-K + pred=fc(h_{d-1}).
// Phase B: attention partials (2 blocks/batch, 4-deep prefetched stream);
//          SECOND-arriving partial block (per-batch LLC counter) combines the
//          two halves into bf16 ctx fragments — no extra barrier.
// Phase C: ctx GEMM + prev_y + LDS split-K reduce + LSTM epilogue.
__global__ __launch_bounds__(512, 1)
void dec_loop(unsigned short* __restrict__ A0, unsigned short* __restrict__ A1,
              const unsigned short* __restrict__ Wdec,    // [256][KCD][512]
              const float* __restrict__ bdec, float* __restrict__ cbuf,
              const unsigned short* __restrict__ Watt,    // [64][KCQ][512]
              unsigned short* __restrict__ qbf,           // [128][1024] bf16
              const unsigned short* __restrict__ enco,    // [128][336][1024]
              unsigned short* __restrict__ hplain,        // [128][1024] bf16
              float* __restrict__ pctx,                   // [2][128][1024] f32
              float* __restrict__ pml,                    // [2][128][2] f32
              unsigned* __restrict__ pcnt,                // [128] arrival counters
              const float* __restrict__ fcW, const float* __restrict__ fcb,
              float* __restrict__ out, unsigned* __restrict__ bar)
{
    __shared__ float smem[8224];   // A: qred[8][4][64]; B: ctxl+mred+lred; C: redc
    __shared__ unsigned cflag_s;
    const int tid = threadIdx.x, l = tid & 63, w = tid >> 6;
    const int rgw = w & 1, ks = w >> 1;
    int x, y; swz(blockIdx.x, x, y);
    const int rg = x*2 + rgw, m0 = rg*16;
    const unsigned short* Bf = Wdec + (size_t)(4*y)*KCD*512 + l*8;
    const unsigned short* Bq = Watt + (size_t)y*KCQ*512 + l*8;

    const int col = l & 15, q4 = l >> 4;
    const int u = y*16 + col;
    const float bi  = bdec[y*64 + col];
    const float bf_ = bdec[y*64 + 16 + col];
    const float bg  = bdec[y*64 + 32 + col];
    const float bo  = bdec[y*64 + 48 + col];
    const int lsh = ((u >> 3) & 3) * 16;
    // attention partial assignment: 2 blocks per batch
    const int ab   = blockIdx.x & 127;        // batch
    const int part = blockIdx.x >> 7;         // S half

    unsigned bstep = 0;
    for (int d = 0; d < Tn; d++){
        unsigned short* Ac = (d & 1) ? A1 : A0;
        unsigned short* An = (d & 1) ? A0 : A1;
        const unsigned short* Af = Ac + (size_t)rg*KCD*512 + l*8;

        // ---------------- phase A ----------------
        floatx4 acc0={0,0,0,0}, acc1={0,0,0,0}, acc2={0,0,0,0}, acc3={0,0,0,0};
        {
            short8 aA[8];
            #pragma unroll
            for (int kk = 0; kk < 8; kk++)
                aA[kk] = ld_cg_s8(Af + (32 + ks*8 + kk)*512);
            floatx4 qa = {0,0,0,0};
            #pragma unroll
            for (int kk = 0; kk < 8; kk++){
                const int kc = 32 + ks*8 + kk;
                short8 b0 = *(const short8*)(Bf + (0*KCD + kc)*512);
                short8 b1 = *(const short8*)(Bf + (1*KCD + kc)*512);
                short8 b2 = *(const short8*)(Bf + (2*KCD + kc)*512);
                short8 b3 = *(const short8*)(Bf + (3*KCD + kc)*512);
                short8 bq = *(const short8*)(Bq + (ks*8 + kk)*512);
                acc0 = __builtin_amdgcn_mfma_f32_16x16x32_bf16(aA[kk], b0, acc0, 0, 0, 0);
                acc1 = __builtin_amdgcn_mfma_f32_16x16x32_bf16(aA[kk], b1, acc1, 0, 0, 0);
                acc2 = __builtin_amdgcn_mfma_f32_16x16x32_bf16(aA[kk], b2, acc2, 0, 0, 0);
                acc3 = __builtin_amdgcn_mfma_f32_16x16x32_bf16(aA[kk], b3, acc3, 0, 0, 0);
                qa   = __builtin_amdgcn_mfma_f32_16x16x32_bf16(aA[kk], bq, qa, 0, 0, 0);
            }
            #pragma unroll
            for (int r = 0; r < 4; r++) smem[(w*4 + r)*64 + l] = qa[r];
        }
        __syncthreads();
        if (ks == 0){   // sum attnq split-K partials, write q
            #pragma unroll
            for (int r = 0; r < 4; r++){
                float s = smem[((0*2+rgw)*4 + r)*64 + l] + smem[((1*2+rgw)*4 + r)*64 + l]
                        + smem[((2*2+rgw)*4 + r)*64 + l] + smem[((3*2+rgw)*4 + r)*64 + l];
                st_cg16(qbf + (size_t)(m0 + q4*4 + r)*Hn + y*16 + col, f2bf(s));
            }
        }
        if (d > 0 && x == 0 && w >= 6){   // pred_{d-1} = fc(h_{d-1})
            const int b = y*2 + (w & 1);
            float p = fcdot(hplain, fcW, b, l);
            if (l == 0){
                float pv = p + fcb[0];
                out[b*Tn + (d-1)] = pv;
                st_cg16(Ac + (((size_t)(b >> 4))*KCD + 64)*512 + (b & 15)*8, f2bf(pv));
            }
        }
        bstep++; gbar3(bar, bstep);

        // ---------------- phase B: attention partials + fused combine ------
        {
            float* ctxl = smem;
            float* mred = smem + 8192;
            float* lred = smem + 8200;
            float qv[16];
            {
                const unsigned short* qp = qbf + (size_t)ab*Hn + l*16;
                uintx4 q0 = ld_cg_u4(qp), q1 = ld_cg_u4(qp + 8);
                unpack8v(q0, qv); unpack8v(q1, qv + 8);
            }
            float mx = -1e30f, lsum = 0.0f;
            float cacc[16];
            #pragma unroll
            for (int i = 0; i < 16; i++) cacc[i] = 0.0f;

            const uintx4* ebase = (const uintx4*)(enco + (size_t)ab*Sn*Hn) + l*2;
            const int sb = part*SHALF + w;   // 21 rows/wave: sb + 8*I, I=0..20
            uintx4 buf_a0, buf_b0, buf_a1, buf_b1, buf_a2, buf_b2, buf_a3, buf_b3;
            BLOAD(0,0)  BLOAD(1,1)  BLOAD(2,2)  BLOAD(3,3)
            BPROC(0) BLOAD(0,4)  BPROC(1) BLOAD(1,5)  BPROC(2) BLOAD(2,6)  BPROC(3) BLOAD(3,7)
            BPROC(0) BLOAD(0,8)  BPROC(1) BLOAD(1,9)  BPROC(2) BLOAD(2,10) BPROC(3) BLOAD(3,11)
            BPROC(0) BLOAD(0,12) BPROC(1) BLOAD(1,13) BPROC(2) BLOAD(2,14) BPROC(3) BLOAD(3,15)
            BPROC(0) BLOAD(0,16) BPROC(1) BLOAD(1,17) BPROC(2) BLOAD(2,18) BPROC(3) BLOAD(3,19)
            BPROC(0) BLOAD(0,20) BPROC(1) BPROC(2) BPROC(3)
            BPROC(0)

            if (l == 0){ mred[w] = mx; lred[w] = lsum; }
            __syncthreads();
            float M = mred[0];
            #pragma unroll
            for (int k = 1; k < 8; k++) M = fmaxf(M, mred[k]);
            float corr2 = expf(mx - M);
            #pragma unroll
            for (int j = 0; j < 16; j++) ctxl[w*1024 + j*64 + l] = cacc[j]*corr2;
            __syncthreads();
            float L = 0.0f;
            #pragma unroll
            for (int k = 0; k < 8; k++) L += lred[k]*expf(mred[k] - M);

            const int u0 = 2*tid;
            float s0 = 0.0f, s1 = 0.0f;
            #pragma unroll
            for (int k = 0; k < 8; k++){
                s0 += ctxl[k*1024 + (u0 & 15)*64 + (u0 >> 4)];
                s1 += ctxl[k*1024 + ((u0+1) & 15)*64 + ((u0+1) >> 4)];
            }
            st_cg64(pctx + ((size_t)part*128 + ab)*1024 + u0, s0, s1);
            if (tid == 0) st_cg64(pml + ((size_t)part*128 + ab)*2, M, lsum*0.0f + L);

            // fused combine: the second-arriving partial block merges halves
            asm volatile("s_waitcnt vmcnt(0)" ::: "memory");
            __syncthreads();
            if (tid == 0){
                unsigned old = __hip_atomic_fetch_add(pcnt + ab*32, 1u,
                                  __ATOMIC_RELAXED, __HIP_MEMORY_SCOPE_AGENT);
                cflag_s = (old == 2u*(unsigned)d + 1u);
            }
            __syncthreads();
            if (cflag_s){
                F2 ml0 = ld_cg64(pml + (size_t)ab*2);
                F2 ml1 = ld_cg64(pml + (size_t)(128 + ab)*2);
                float Mg = fmaxf(ml0.f[0], ml1.f[0]);
                float w0 = expf(ml0.f[0] - Mg), w1 = expf(ml1.f[0] - Mg);
                float invL = 1.0f / (ml0.f[1]*w0 + ml1.f[1]*w1);
                F2 c0 = ld_cg64(pctx + (size_t)ab*1024 + u0);
                F2 c1 = ld_cg64(pctx + ((size_t)128 + ab)*1024 + u0);
                float v0 = (c0.f[0]*w0 + c1.f[0]*w1)*invL;
                float v1 = (c0.f[1]*w0 + c1.f[1]*w1)*invL;
                unsigned cvu = (unsigned)f2bf(v0) | ((unsigned)f2bf(v1) << 16);
                const int kcw = u0 >> 5;
                const int lanep2 = (ab & 15) + ((u0 >> 3) & 3)*16;
                st_cg32(Ac + ((((size_t)(ab >> 4))*KCD + kcw)*64 + lanep2)*8 + (u0 & 7), cvu);
            }
        }
        bstep++; gbar3(bar, bstep);

        // ---------------- phase C ----------------
        {
            short8 aC[8];
            #pragma unroll
            for (int kk = 0; kk < 8; kk++)
                aC[kk] = ld_cg_s8(Af + (ks*8 + kk)*512);
            #pragma unroll
            for (int kk = 0; kk < 8; kk++){
                const int kc = ks*8 + kk;
                short8 b0 = *(const short8*)(Bf + (0*KCD + kc)*512);
                short8 b1 = *(const short8*)(Bf + (1*KCD + kc)*512);
                short8 b2 = *(const short8*)(Bf + (2*KCD + kc)*512);
                short8 b3 = *(const short8*)(Bf + (3*KCD + kc)*512);
                acc0 = __builtin_amdgcn_mfma_f32_16x16x32_bf16(aC[kk], b0, acc0, 0, 0, 0);
                acc1 = __builtin_amdgcn_mfma_f32_16x16x32_bf16(aC[kk], b1, acc1, 0, 0, 0);
                acc2 = __builtin_amdgcn_mfma_f32_16x16x32_bf16(aC[kk], b2, acc2, 0, 0, 0);
                acc3 = __builtin_amdgcn_mfma_f32_16x16x32_bf16(aC[kk], b3, acc3, 0, 0, 0);
            }
            if (ks == 3){   // prev_y + pad chunk
                short8 a  = ld_cg_s8(Af + 64*512);
                short8 b0 = *(const short8*)(Bf + (0*KCD + 64)*512);
                short8 b1 = *(const short8*)(Bf + (1*KCD + 64)*512);
                short8 b2 = *(const short8*)(Bf + (2*KCD + 64)*512);
                short8 b3 = *(const short8*)(Bf + (3*KCD + 64)*512);
                acc0 = __builtin_amdgcn_mfma_f32_16x16x32_bf16(a, b0, acc0, 0, 0, 0);
                acc1 = __builtin_amdgcn_mfma_f32_16x16x32_bf16(a, b1, acc1, 0, 0, 0);
                acc2 = __builtin_amdgcn_mfma_f32_16x16x32_bf16(a, b2, acc2, 0, 0, 0);
                acc3 = __builtin_amdgcn_mfma_f32_16x16x32_bf16(a, b3, acc3, 0, 0, 0);
            }
        }
        if (ks != 0){
            float* rp = smem + ((ks-1)*2 + rgw)*1024;
            #pragma unroll
            for (int r = 0; r < 4; r++){
                rp[( 0 + r)*64 + l] = acc0[r];
                rp[( 4 + r)*64 + l] = acc1[r];
                rp[( 8 + r)*64 + l] = acc2[r];
                rp[(12 + r)*64 + l] = acc3[r];
            }
        }
        __syncthreads();
        if (ks == 0){
            const float* r0 = smem + rgw*1024;
            const float* r1 = smem + (2 + rgw)*1024;
            const float* r2 = smem + (4 + rgw)*1024;
            #pragma unroll
            for (int r = 0; r < 4; r++){
                acc0[r] += r0[( 0+r)*64 + l] + r1[( 0+r)*64 + l] + r2[( 0+r)*64 + l];
                acc1[r] += r0[( 4+r)*64 + l] + r1[( 4+r)*64 + l] + r2[( 4+r)*64 + l];
                acc2[r] += r0[( 8+r)*64 + l] + r1[( 8+r)*64 + l] + r2[( 8+r)*64 + l];
                acc3[r] += r0[(12+r)*64 + l] + r1[(12+r)*64 + l] + r2[(12+r)*64 + l];
            }
            #pragma unroll
            for (int r = 0; r < 4; r++){
                const int m = m0 + q4*4 + r;
                float gi = acc0[r] + bi;
                float gf = acc1[r] + bf_;
                float gg = acc2[r] + bg;
                float go = acc3[r] + bo;
                float co = cbuf[(size_t)m*Hn + u];
                float cn = sigmoidf_(gf)*co + sigmoidf_(gi)*tanhf(gg);
                float hv = sigmoidf_(go)*tanhf(cn);
                cbuf[(size_t)m*Hn + u] = cn;
                unsigned short hb = f2bf(hv);
                const int lanep = (q4*4 + r) + lsh;
                st_cg16(An + (((size_t)rg*KCD + 32 + (u >> 5))*64 + lanep)*8 + (u & 7), hb);
                st_cg16(hplain + (size_t)m*Hn + u, hb);
            }
        }
        bstep++; gbar3(bar, bstep);
    }

    // final pred: out[:, Tn-1] = fc(h_{Tn-1})
    if (x == 0 && w >= 6){
        const int b = y*2 + (w & 1);
        float p = fcdot(hplain, fcW, b, l);
        if (l == 0) out[b*Tn + (Tn - 1)] = p + fcb[0];
    }
}

extern "C" void kernel_launch(void* const* d_in, const int* in_sizes, int n_in,
                              void* d_out, int out_size, void* d_ws, size_t ws_size,
                              hipStream_t stream){
    const float* src  = (const float*)d_in[0];
    const float* eWih = (const float*)d_in[1];
    const float* eWhh = (const float*)d_in[2];
    const float* ebih = (const float*)d_in[3];
    const float* ebhh = (const float*)d_in[4];
    const float* dWih = (const float*)d_in[5];
    const float* dWhh = (const float*)d_in[6];
    const float* dbih = (const float*)d_in[7];
    const float* dbhh = (const float*)d_in[8];
    const float* attnW= (const float*)d_in[9];
    const float* fcW  = (const float*)d_in[10];
    const float* fcb  = (const float*)d_in[11];
    float* out = (float*)d_out;

    char* base = (char*)d_ws;
    auto alloc = [&](size_t bytes){ void* p = base; base += (bytes + 255) & ~255ull; return p; };
    unsigned short* Wencf = (unsigned short*)alloc((size_t)256*KCE*512*2);
    float*          benc  = (float*)alloc(G4*4);
    unsigned short* Wdecf = (unsigned short*)alloc((size_t)256*KCD*512*2);
    float*          bdec  = (float*)alloc(G4*4);
    unsigned short* Wattf = (unsigned short*)alloc((size_t)64*KCQ*512*2);
    unsigned short* srcf  = (unsigned short*)alloc((size_t)Sn*8*2*512*2);
    unsigned short* enco  = (unsigned short*)alloc((size_t)Bn*Sn*Hn*2);
    unsigned short* hf0   = (unsigned short*)alloc((size_t)8*32*512*2);
    unsigned short* hf1   = (unsigned short*)alloc((size_t)8*32*512*2);
    float*          cbuf  = (float*)alloc((size_t)Bn*Hn*4);
    unsigned short* A0f   = (unsigned short*)alloc((size_t)8*KCD*512*2);
    unsigned short* A1f   = (unsigned short*)alloc((size_t)8*KCD*512*2);
    unsigned short* qbf   = (unsigned short*)alloc((size_t)Bn*Hn*2);
    unsigned short* hplain= (unsigned short*)alloc((size_t)Bn*Hn*2);
    float*          pctx  = (float*)alloc((size_t)2*128*1024*4);
    float*          pml   = (float*)alloc((size_t)2*128*2*4);
    unsigned*       bars  = (unsigned*)alloc((size_t)32768*4);
    unsigned*       pcnt  = (unsigned*)alloc((size_t)4096*4);

    conv_srcf<<<2048, 256, 0, stream>>>(src, srcf);
    pack_encf<<<4096, 256, 0, stream>>>(eWih, eWhh, ebih, ebhh, Wencf, benc);
    pack_decf<<<8192, 256, 0, stream>>>(dWih, dWhh, dbih, dbhh, Wdecf, bdec);
    pack_attnf<<<1024, 256, 0, stream>>>(attnW, Wattf);
    init_ws<<<1040, 256, 0, stream>>>(hf0, cbuf, A0f, A1f, bars, pcnt);

    enc_loop<<<NBLK, 256, 0, stream>>>(srcf, Wencf, benc, cbuf, hf0, hf1,
                                       enco, A0f, bars);
    dec_loop<<<NBLK, 512, 0, stream>>>(A0f, A1f, Wdecf, bdec, cbuf, Wattf,
                                       qbf, enco, hplain, pctx, pml, pcnt,
                                       fcW, fcb, out, bars + 16384);
}